// Round 9
// baseline (1730.183 us; speedup 1.0000x reference)
//
#include <hip/hip_runtime.h>
#include <hip/hip_fp16.h>

#define N_NODES 100000
#define N_EDGES 3200000
#define N_GRAPHS 256
#define NODE_DIM 7
#define HID 64
#define NLAY 3
#define EPSV 1e-5f

#define NOCT 8
#define OCT_W 12800                  // 100 sub-bins of 128 nodes per octant
#define BIN_CAP 480000               // per-octant int2 capacity (mean ~409.6K)
#define SBW 128                      // sub-bin width (nodes)
#define NSB 782                      // ceil(100000/128)
#define SB_PER_OCT 100
#define CAP2 4608                    // per-sub-bin packed capacity (mean 4096, +8 sigma)
#define QDIV 25000                   // src quartile divisor
#define NKEY (SBW * 4)               // (dst_local, quartile) sort keys

static __device__ __forceinline__ void f4add(float4& a, const float4& b) {
    a.x += b.x; a.y += b.y; a.z += b.z; a.w += b.w;
}

// ---------------- graph-structure kernels (run once per call) ----------------

// batch is sorted: per-graph counts via binary search, zero atomics.
__global__ __launch_bounds__(256) void k_gcnt(const int* __restrict__ batch, int* __restrict__ gcnt) {
    __shared__ int start[N_GRAPHS + 1];
    int g = threadIdx.x;
    int lo = 0, hi = N_NODES;
    while (lo < hi) { int mid = (lo + hi) >> 1; if (batch[mid] < g) lo = mid + 1; else hi = mid; }
    start[g] = lo;
    if (g == 0) start[N_GRAPHS] = N_NODES;
    __syncthreads();
    gcnt[g] = start[g + 1] - start[g];
}

// Pass 1: bin edges by dst octant (width 12800). Dense int2 appends.
__global__ __launch_bounds__(256) void k_bin(const int* __restrict__ src, const int* __restrict__ dst,
                                             int* __restrict__ gcur, int2* __restrict__ bins) {
    __shared__ int lcnt[NOCT];
    __shared__ int lbase[NOCT];
    const int t = threadIdx.x;
    const int NC = N_EDGES / 4 / 256;              // 3125 chunks of 1024 edges
    for (int chunk = blockIdx.x; chunk < NC; chunk += gridDim.x) {
        if (t < NOCT) lcnt[t] = 0;
        __syncthreads();
        int i4 = chunk * 256 + t;
        int4 d = ((const int4*)dst)[i4];
        int4 s = ((const int4*)src)[i4];
        int o0 = d.x / OCT_W, o1 = d.y / OCT_W, o2 = d.z / OCT_W, o3 = d.w / OCT_W;
        int r0 = atomicAdd(&lcnt[o0], 1);
        int r1 = atomicAdd(&lcnt[o1], 1);
        int r2 = atomicAdd(&lcnt[o2], 1);
        int r3 = atomicAdd(&lcnt[o3], 1);
        __syncthreads();
        if (t < NOCT) lbase[t] = lcnt[t] ? atomicAdd(&gcur[t], lcnt[t]) : 0;
        __syncthreads();
        bins[(size_t)o0 * BIN_CAP + lbase[o0] + r0] = make_int2(d.x, s.x);
        bins[(size_t)o1 * BIN_CAP + lbase[o1] + r1] = make_int2(d.y, s.y);
        bins[(size_t)o2 * BIN_CAP + lbase[o2] + r2] = make_int2(d.z, s.z);
        bins[(size_t)o3 * BIN_CAP + lbase[o3] + r3] = make_int2(d.w, s.w);
        __syncthreads();
    }
}

// Pass 2a: octant bins -> per-sub-bin packed lists (src | dst_local<<17).
__global__ __launch_bounds__(256) void k_bin2a(const int2* __restrict__ bins1, const int* __restrict__ gcur,
                                               int* __restrict__ gcur2, unsigned* __restrict__ bins2) {
    __shared__ int lcnt[SB_PER_OCT];
    __shared__ int lbase[SB_PER_OCT];
    const int o = blockIdx.x & 7;
    const int slice = blockIdx.x >> 3;             // 0..31
    const int t = threadIdx.x;
    const int n = gcur[o];
    const int2* bp = bins1 + (size_t)o * BIN_CAP;
    const int sbBase = o * SB_PER_OCT;
    for (int start = slice * 2048; start < n; start += 32 * 2048) {
        if (t < SB_PER_OCT) lcnt[t] = 0;
        __syncthreads();
        int r[8]; int sbl[8]; unsigned pk[8];
#pragma unroll
        for (int j = 0; j < 8; j++) {
            int idx = start + j * 256 + t;
            if (idx < n) {
                int2 e = bp[idx];
                sbl[j] = (e.x - o * OCT_W) >> 7;
                pk[j] = (unsigned)e.y | ((unsigned)(e.x & (SBW - 1)) << 17);
                r[j] = atomicAdd(&lcnt[sbl[j]], 1);
            } else sbl[j] = -1;
        }
        __syncthreads();
        if (t < SB_PER_OCT) lbase[t] = lcnt[t] ? atomicAdd(&gcur2[sbBase + t], lcnt[t]) : 0;
        __syncthreads();
#pragma unroll
        for (int j = 0; j < 8; j++)
            if (sbl[j] >= 0)
                bins2[(size_t)(sbBase + sbl[j]) * CAP2 + lbase[sbl[j]] + r[j]] = pk[j];
        __syncthreads();
    }
}

// Pass 2b: per sub-bin LDS counting sort by (dst_local, src_quartile).
// CSR for free + quartile-ordered edge segments (soft L2 phase locality for
// k_agg: each src quartile's table slice is 3.2MB < 4MB L2/XCD).
__global__ __launch_bounds__(256) void k_bin2s(unsigned* __restrict__ bins2, const int* __restrict__ gcur2,
                                               int* __restrict__ degE, float* __restrict__ dinv,
                                               int* __restrict__ rowptr2) {
    __shared__ unsigned raw[CAP2];
    __shared__ unsigned srt[CAP2];
    __shared__ int cnt[NKEY];
    __shared__ int cur[NKEY];
    const int sb = blockIdx.x;
    const int t = threadIdx.x;
    const int base = sb * SBW;
    int n = gcur2[sb]; if (n > CAP2) n = CAP2;
    unsigned* seg = bins2 + (size_t)sb * CAP2;
    for (int i = t; i < n; i += 256) raw[i] = seg[i];
    for (int i = t; i < NKEY; i += 256) cnt[i] = 0;
    __syncthreads();
    for (int i = t; i < n; i += 256) {
        unsigned p = raw[i];
        int key = (int)(p >> 17) * 4 + (int)((p & 0x1FFFFu) / QDIV);
        atomicAdd(&cnt[key], 1);
    }
    __syncthreads();
    if (t == 0) {
        int run = 0;
        for (int i = 0; i < NKEY; i++) { cur[i] = run; run += cnt[i]; }
    }
    __syncthreads();
    if (t < SBW && base + t < N_NODES) {
        int deg = cnt[t * 4] + cnt[t * 4 + 1] + cnt[t * 4 + 2] + cnt[t * 4 + 3];
        degE[base + t]    = deg;
        dinv[base + t]    = rsqrtf((float)(deg + 1));       // +1 self-loop
        rowptr2[base + t] = sb * CAP2 + cur[t * 4];
    }
    __syncthreads();
    for (int i = t; i < n; i += 256) {
        unsigned p = raw[i];
        int key = (int)(p >> 17) * 4 + (int)((p & 0x1FFFFu) / QDIV);
        srt[atomicAdd(&cur[key], 1)] = p;
    }
    __syncthreads();
    for (int i = t; i < n; i += 256) seg[i] = srt[i];
}

// ---------------- per-layer kernels ----------------

// h0 = x @ Win + bin
__global__ __launch_bounds__(256) void k_h0(const float* __restrict__ x, const float* __restrict__ Win,
                                            const float* __restrict__ b, float* __restrict__ h) {
    int i = blockIdx.x * 256 + threadIdx.x;
    if (i >= N_NODES * HID) return;
    int v = i >> 6, j = i & 63;
    float acc = b[j];
#pragma unroll
    for (int k = 0; k < NODE_DIM; k++) acc += x[v * NODE_DIM + k] * Win[k * HID + j];
    h[i] = acc;
}

// y = fp16( (h @ W) * dinv[:,None] ) ; 64 nodes per block.
// W read directly from global (16KB, L1-resident across blocks) -> LDS only
// 16KB for the h tile; acc[4][4] register blocking, k4 outer so W is loaded
// once per k-quad. High occupancy (low LDS + low VGPR).
__global__ __launch_bounds__(256) void k_xw(const float* __restrict__ h, const float* __restrict__ W,
                                            const float* __restrict__ dinv, __half* __restrict__ y) {
    __shared__ float Hs[64][HID];                  // 16KB
    int t = threadIdx.x;
    int nb = blockIdx.x * 64;
#pragma unroll
    for (int it = 0; it < 4; it++) {
        int i = t + it * 256;                      // float4 index, 1024 total
        int r = i >> 4, c4 = i & 15;
        int node = nb + r;
        float4 hv = make_float4(0.f, 0.f, 0.f, 0.f);
        if (node < N_NODES) hv = ((const float4*)h)[(size_t)node * 16 + c4];
        ((float4*)&Hs[r][0])[c4] = hv;
    }
    __syncthreads();
    const int j = t & 63;
    const int r0 = t >> 6;                         // wave-uniform 0..3
    float acc[4][4] = {};                          // [o][row]
#pragma unroll
    for (int k4 = 0; k4 < 16; k4++) {
        float w0 = W[(k4 * 4 + 0) * HID + j];
        float w1 = W[(k4 * 4 + 1) * HID + j];
        float w2 = W[(k4 * 4 + 2) * HID + j];
        float w3 = W[(k4 * 4 + 3) * HID + j];
#pragma unroll
        for (int o = 0; o < 4; o++) {
            int ra = r0 + o * 16;
            float4 h0 = ((const float4*)&Hs[ra][0])[k4];
            float4 h1 = ((const float4*)&Hs[ra + 4][0])[k4];
            float4 h2 = ((const float4*)&Hs[ra + 8][0])[k4];
            float4 h3 = ((const float4*)&Hs[ra + 12][0])[k4];
            acc[o][0] += h0.x * w0 + h0.y * w1 + h0.z * w2 + h0.w * w3;
            acc[o][1] += h1.x * w0 + h1.y * w1 + h1.z * w2 + h1.w * w3;
            acc[o][2] += h2.x * w0 + h2.y * w1 + h2.z * w2 + h2.w * w3;
            acc[o][3] += h3.x * w0 + h3.y * w1 + h3.z * w2 + h3.w * w3;
        }
    }
#pragma unroll
    for (int o = 0; o < 4; o++) {
        int n0 = nb + r0 + o * 16;
        if (n0 < N_NODES)      y[(size_t)n0 * HID + j]        = __float2half(acc[o][0] * dinv[n0]);
        if (n0 + 4 < N_NODES)  y[(size_t)(n0 + 4) * HID + j]  = __float2half(acc[o][1] * dinv[n0 + 4]);
        if (n0 + 8 < N_NODES)  y[(size_t)(n0 + 8) * HID + j]  = __float2half(acc[o][2] * dinv[n0 + 8]);
        if (n0 + 12 < N_NODES) y[(size_t)(n0 + 12) * HID + j] = __float2half(acc[o][3] * dinv[n0 + 12]);
    }
}

// c[v] = dinv[v]*(y[v] + sum_{in-edges} y[s]) + bias ; fused per-graph S1/S2 stats.
// One wave per node. fp16 rows = 128B = 8 lanes x uint4; lane-group q (8 lanes)
// gathers edge e+q from the sorted packed segment (src = p & 0x1FFFF).
// 32-edge unroll: 4 independent 1KB gathers in flight. f32 accumulate.
__global__ __launch_bounds__(256) void k_agg(const __half* __restrict__ y, const int* __restrict__ rowptr2,
                                             const int* __restrict__ degE, const unsigned* __restrict__ cols,
                                             const float* __restrict__ dinv, const float* __restrict__ bias,
                                             const int* __restrict__ batch, float* __restrict__ c,
                                             float* __restrict__ gS1, float* __restrict__ gS2) {
    __shared__ float sh1[4][HID];
    __shared__ float sh2[4][HID];
    __shared__ int shg[4];
    const int t = threadIdx.x;
    const int w = t >> 6;          // wave in block
    const int lane = t & 63;
    const int v = blockIdx.x * 4 + w;    // grid covers N_NODES exactly
    const int q = lane >> 3;       // edge group 0..7
    const int f8 = lane & 7;       // uint4 slot within 128B row
    const uint4* __restrict__ y16 = (const uint4*)y;

    float a[8] = {0.f,0.f,0.f,0.f,0.f,0.f,0.f,0.f};
    float b[8] = {0.f,0.f,0.f,0.f,0.f,0.f,0.f,0.f};

    auto unpack_add = [&](float* acc, uint4 u) {
        float2 f0 = __half22float2(*(const __half2*)&u.x);
        float2 f1 = __half22float2(*(const __half2*)&u.y);
        float2 f2 = __half22float2(*(const __half2*)&u.z);
        float2 f3 = __half22float2(*(const __half2*)&u.w);
        acc[0] += f0.x; acc[1] += f0.y;
        acc[2] += f1.x; acc[3] += f1.y;
        acc[4] += f2.x; acc[5] += f2.y;
        acc[6] += f3.x; acc[7] += f3.y;
    };

    if (q == 0) unpack_add(a, y16[(size_t)v * 8 + f8]);     // self-loop
    int e0 = rowptr2[v], e1 = e0 + degE[v];
    int e = e0;
    if (e + 31 < e1) {
        int s0 = cols[e + q] & 0x1FFFF, s1 = cols[e + 8 + q] & 0x1FFFF;
        int s2 = cols[e + 16 + q] & 0x1FFFF, s3 = cols[e + 24 + q] & 0x1FFFF;
        for (;;) {
            uint4 u0 = y16[(size_t)s0 * 8 + f8];
            uint4 u1 = y16[(size_t)s1 * 8 + f8];
            uint4 u2 = y16[(size_t)s2 * 8 + f8];
            uint4 u3 = y16[(size_t)s3 * 8 + f8];
            e += 32;
            bool more = (e + 31 < e1);
            if (more) {
                s0 = cols[e + q] & 0x1FFFF; s1 = cols[e + 8 + q] & 0x1FFFF;
                s2 = cols[e + 16 + q] & 0x1FFFF; s3 = cols[e + 24 + q] & 0x1FFFF;
            }
            unpack_add(a, u0);
            unpack_add(b, u1);
            unpack_add(a, u2);
            unpack_add(b, u3);
            if (!more) break;
        }
    }
    if (e + 15 < e1) {
        int s0 = cols[e + q] & 0x1FFFF, s1 = cols[e + 8 + q] & 0x1FFFF;
        uint4 u0 = y16[(size_t)s0 * 8 + f8];
        uint4 u1 = y16[(size_t)s1 * 8 + f8];
        unpack_add(a, u0);
        unpack_add(b, u1);
        e += 16;
    }
    if (e + 7 < e1) {
        unpack_add(a, y16[(size_t)(cols[e + q] & 0x1FFFF) * 8 + f8]);
        e += 8;
    }
    if (e + q < e1) {
        unpack_add(b, y16[(size_t)(cols[e + q] & 0x1FFFF) * 8 + f8]);
    }
#pragma unroll
    for (int k = 0; k < 8; k++) a[k] += b[k];
    // reduce across the 8 lane-groups (masks 8, 16, 32)
#pragma unroll
    for (int k = 0; k < 8; k++) {
        a[k] += __shfl_xor(a[k], 8);
        a[k] += __shfl_xor(a[k], 16);
        a[k] += __shfl_xor(a[k], 32);
    }

    if (q == 0) {   // lanes 0..7 hold features [f8*8 .. f8*8+7]
        float dv = dinv[v];
        float4 bb0 = ((const float4*)bias)[f8 * 2 + 0];
        float4 bb1 = ((const float4*)bias)[f8 * 2 + 1];
        float cv[8];
        cv[0] = dv * a[0] + bb0.x; cv[1] = dv * a[1] + bb0.y;
        cv[2] = dv * a[2] + bb0.z; cv[3] = dv * a[3] + bb0.w;
        cv[4] = dv * a[4] + bb1.x; cv[5] = dv * a[5] + bb1.y;
        cv[6] = dv * a[6] + bb1.z; cv[7] = dv * a[7] + bb1.w;
        float4* c4 = (float4*)c;
        c4[(size_t)v * 16 + f8 * 2 + 0] = make_float4(cv[0], cv[1], cv[2], cv[3]);
        c4[(size_t)v * 16 + f8 * 2 + 1] = make_float4(cv[4], cv[5], cv[6], cv[7]);
#pragma unroll
        for (int k = 0; k < 8; k++) {
            sh1[w][f8 * 8 + k] = cv[k];
            sh2[w][f8 * 8 + k] = cv[k] * cv[k];
        }
        if (f8 == 0) shg[w] = batch[v];
    }
    __syncthreads();
    if (w == 0) {   // one wave reduces block stats
        int g0 = shg[0];
        bool uni = (shg[1] == g0) && (shg[2] == g0) && (shg[3] == g0);
        if (uni) {
            float s1 = sh1[0][lane] + sh1[1][lane] + sh1[2][lane] + sh1[3][lane];
            float s2 = sh2[0][lane] + sh2[1][lane] + sh2[2][lane] + sh2[3][lane];
            atomicAdd(&gS1[g0 * HID + lane], s1);
            atomicAdd(&gS2[g0 * HID + lane], s2);
        } else {
#pragma unroll
            for (int ww = 0; ww < 4; ww++) {
                atomicAdd(&gS1[shg[ww] * HID + lane], sh1[ww][lane]);
                atomicAdd(&gS2[shg[ww] * HID + lane], sh2[ww][lane]);
            }
        }
    }
}

// per-graph mean / inv-std.  var = S2/cnt - 2*s*m^2 + s^2*m^2
__global__ __launch_bounds__(256) void k_stats(const float* __restrict__ gS1, const float* __restrict__ gS2,
                                               const int* __restrict__ gcnt, const float* __restrict__ gnS_l,
                                               float* __restrict__ gmean, float* __restrict__ ginv) {
    int i = blockIdx.x * 256 + threadIdx.x;
    if (i >= N_GRAPHS * HID) return;
    int g = i >> 6, j = i & 63;
    float cnt = fmaxf((float)gcnt[g], 1.f);
    float m = gS1[i] / cnt;
    float s = gnS_l[j];
    float var = gS2[i] / cnt - 2.f * s * m * m + s * s * m * m;
    gmean[i] = m;
    ginv[i] = rsqrtf(var + EPSV);
}

// h += relu(gnW*(c - s*mean)*invstd + gnB), float4 lanes; 16 nodes/block;
// optional block-reduced graph-emb accumulation.
__global__ __launch_bounds__(256) void k_update(const float* __restrict__ c, const int* __restrict__ batch,
                                                const float* __restrict__ gmean, const float* __restrict__ ginv,
                                                const float* __restrict__ gnW_l, const float* __restrict__ gnB_l,
                                                const float* __restrict__ gnS_l, float* __restrict__ h,
                                                float* __restrict__ gemb, int accum_emb) {
    __shared__ float4 shh[16][16];
    __shared__ int shg[16];
    __shared__ int uniS;
    int t = threadIdx.x;
    int i = blockIdx.x * 256 + t;          // float4 index; grid covers N_NODES*16 exactly
    int v = i >> 4, f = i & 15, r = t >> 4;
    int g = batch[v];
    float4 c4 = ((const float4*)c)[i];
    float4 m4 = ((const float4*)gmean)[g * 16 + f];
    float4 i4 = ((const float4*)ginv)[g * 16 + f];
    float4 w4 = ((const float4*)gnW_l)[f];
    float4 b4 = ((const float4*)gnB_l)[f];
    float4 s4 = ((const float4*)gnS_l)[f];
    float4 h4 = ((const float4*)h)[i];
    float4 hn;
    hn.x = h4.x + fmaxf(w4.x * (c4.x - s4.x * m4.x) * i4.x + b4.x, 0.f);
    hn.y = h4.y + fmaxf(w4.y * (c4.y - s4.y * m4.y) * i4.y + b4.y, 0.f);
    hn.z = h4.z + fmaxf(w4.z * (c4.z - s4.z * m4.z) * i4.z + b4.z, 0.f);
    hn.w = h4.w + fmaxf(w4.w * (c4.w - s4.w * m4.w) * i4.w + b4.w, 0.f);
    ((float4*)h)[i] = hn;
    if (accum_emb) {
        shh[r][f] = hn;
        if (f == 0) shg[r] = g;
        if (t == 0) uniS = 1;
        __syncthreads();
        if (t < 15 && shg[t + 1] != shg[0]) uniS = 0;
        __syncthreads();
        if (uniS) {
            if (t < 128) f4add(shh[t >> 4][t & 15], shh[(t >> 4) + 8][t & 15]);
            __syncthreads();
            if (t < 64) f4add(shh[t >> 4][t & 15], shh[(t >> 4) + 4][t & 15]);
            __syncthreads();
            if (t < 32) f4add(shh[t >> 4][t & 15], shh[(t >> 4) + 2][t & 15]);
            __syncthreads();
            if (t < 16) {
                f4add(shh[0][t], shh[1][t]);
                float4 s = shh[0][t];
                int g0 = shg[0];
                atomicAdd(&gemb[g0 * HID + t * 4 + 0], s.x);
                atomicAdd(&gemb[g0 * HID + t * 4 + 1], s.y);
                atomicAdd(&gemb[g0 * HID + t * 4 + 2], s.z);
                atomicAdd(&gemb[g0 * HID + t * 4 + 3], s.w);
            }
        } else if (t < 16) {
#pragma unroll
            for (int rr = 0; rr < 16; rr++) {
                float4 s = shh[rr][t];
                int gg = shg[rr];
                atomicAdd(&gemb[gg * HID + t * 4 + 0], s.x);
                atomicAdd(&gemb[gg * HID + t * 4 + 1], s.y);
                atomicAdd(&gemb[gg * HID + t * 4 + 2], s.z);
                atomicAdd(&gemb[gg * HID + t * 4 + 3], s.w);
            }
        }
    }
}

// classifier head: emb = gemb/cnt ; z = relu(emb@W1+b1) ; out = z@W2+b2
__global__ __launch_bounds__(64) void k_cls(const float* __restrict__ gemb, const int* __restrict__ gcnt,
                                            const float* __restrict__ W1, const float* __restrict__ b1,
                                            const float* __restrict__ W2, const float* __restrict__ b2,
                                            float* __restrict__ out) {
    __shared__ float emb[HID];
    __shared__ float z[HID];
    int g = blockIdx.x, j = threadIdx.x;
    float cnt = fmaxf((float)gcnt[g], 1.f);
    emb[j] = gemb[g * HID + j] / cnt;
    __syncthreads();
    float acc = b1[j];
    for (int k = 0; k < HID; k++) acc += emb[k] * W1[k * HID + j];
    z[j] = fmaxf(acc, 0.f);
    __syncthreads();
    if (j < 2) {
        float o = b2[j];
        for (int k = 0; k < HID; k++) o += z[k] * W2[k * 2 + j];
        out[g * 2 + j] = o;
    }
}

extern "C" void kernel_launch(void* const* d_in, const int* in_sizes, int n_in,
                              void* d_out, int out_size, void* d_ws, size_t ws_size,
                              hipStream_t stream) {
    const float* x     = (const float*)d_in[0];
    const int*   ei    = (const int*)d_in[1];
    const int*   src   = ei;
    const int*   dst   = ei + N_EDGES;
    const int*   batch = (const int*)d_in[2];
    const float* Win   = (const float*)d_in[3];
    const float* bin_  = (const float*)d_in[4];
    const float* convW = (const float*)d_in[5];
    const float* convB = (const float*)d_in[6];
    const float* gnW   = (const float*)d_in[7];
    const float* gnB   = (const float*)d_in[8];
    const float* gnS   = (const float*)d_in[9];
    const float* W1    = (const float*)d_in[10];
    const float* b1    = (const float*)d_in[11];
    const float* W2    = (const float*)d_in[12];
    const float* b2    = (const float*)d_in[13];
    float* out = (float*)d_out;

    char* ws = (char*)d_ws;
    size_t off = 0;
    auto alloc = [&](size_t bytes) -> void* {
        void* p = ws + off;
        off = (off + bytes + 255) & ~(size_t)255;
        return p;
    };
    // ---- zeroed region (one memset) ----
    int*   gcur   = (int*)alloc(NOCT * 4);
    int*   gcur2  = (int*)alloc((size_t)NSB * 4);
    float* gS1    = (float*)alloc((size_t)NLAY * N_GRAPHS * HID * 4);
    float* gS2    = (float*)alloc((size_t)NLAY * N_GRAPHS * HID * 4);
    float* gemb   = (float*)alloc((size_t)N_GRAPHS * HID * 4);
    size_t zeroBytes = off;
    // ---- rest ----
    int*   gcnt   = (int*)alloc((size_t)N_GRAPHS * 4);
    int*   degE   = (int*)alloc((size_t)N_NODES * 4);
    float* dinv   = (float*)alloc((size_t)N_NODES * 4);
    int*   rowptr2= (int*)alloc((size_t)N_NODES * 4);
    float* h      = (float*)alloc((size_t)N_NODES * HID * 4);   // 25.6 MB
    __half* y     = (__half*)alloc((size_t)N_NODES * HID * 2);  // 12.8 MB
    float* c      = (float*)alloc((size_t)N_NODES * HID * 4);   // 25.6 MB
    unsigned* bins2 = (unsigned*)alloc((size_t)NSB * CAP2 * 4); // 14.4 MB (persists all layers)
    float* gmean  = (float*)alloc((size_t)N_GRAPHS * HID * 4);
    float* ginv   = (float*)alloc((size_t)N_GRAPHS * HID * 4);
    // bins1 (30.7 MB int2) aliases h+y (38.4 MB): dead before k_h0/k_xw write them.
    int2*  bins1  = (int2*)h;
    (void)ws_size; (void)in_sizes; (void)n_in; (void)out_size;

    hipMemsetAsync(d_ws, 0, zeroBytes, stream);

    const int NHB = (N_NODES * HID + 255) / 256;     // 25000

    k_gcnt<<<1, 256, 0, stream>>>(batch, gcnt);
    k_bin<<<800, 256, 0, stream>>>(src, dst, gcur, bins1);
    k_bin2a<<<256, 256, 0, stream>>>(bins1, gcur, gcur2, bins2);
    k_bin2s<<<NSB, 256, 0, stream>>>(bins2, gcur2, degE, dinv, rowptr2);

    k_h0<<<NHB, 256, 0, stream>>>(x, Win, bin_, h);

    const int XWB = (N_NODES + 63) / 64;             // 1563
    for (int l = 0; l < NLAY; l++) {
        const float* Wl   = convW + (size_t)l * HID * HID;
        const float* bl   = convB + (size_t)l * HID;
        const float* gnWl = gnW + (size_t)l * HID;
        const float* gnBl = gnB + (size_t)l * HID;
        const float* gnSl = gnS + (size_t)l * HID;
        float* S1l = gS1 + (size_t)l * N_GRAPHS * HID;
        float* S2l = gS2 + (size_t)l * N_GRAPHS * HID;

        k_xw<<<XWB, 256, 0, stream>>>(h, Wl, dinv, y);
        k_agg<<<N_NODES / 4, 256, 0, stream>>>(y, rowptr2, degE, bins2, dinv, bl, batch, c, S1l, S2l);
        k_stats<<<(N_GRAPHS * HID + 255) / 256, 256, 0, stream>>>(S1l, S2l, gcnt, gnSl, gmean, ginv);
        k_update<<<N_NODES * 16 / 256, 256, 0, stream>>>(c, batch, gmean, ginv, gnWl, gnBl, gnSl, h, gemb,
                                                         (l == NLAY - 1) ? 1 : 0);
    }

    k_cls<<<N_GRAPHS, 64, 0, stream>>>(gemb, gcnt, W1, b1, W2, b2, out);
}

// Round 10
// 551.718 us; speedup vs baseline: 3.1360x; 3.1360x over previous
//
#include <hip/hip_runtime.h>
#include <hip/hip_fp16.h>

#define N_NODES 100000
#define N_EDGES 3200000
#define N_GRAPHS 256
#define NODE_DIM 7
#define HID 64
#define NLAY 3
#define EPSV 1e-5f

#define NOCT 8
#define OCT_W 12800                  // 100 sub-bins of 128 nodes per octant
#define BIN_CAP 480000               // per-octant int2 capacity (mean ~409.6K)
#define SBW 128                      // sub-bin width (nodes)
#define NSB 782                      // ceil(100000/128)
#define SB_PER_OCT 100
#define CAP2 4608                    // per-sub-bin packed capacity (mean 4096, +8 sigma)
#define QDIV 25000                   // src quartile divisor
#define NKEY (SBW * 4)               // (dst_local, quartile) sort keys

static __device__ __forceinline__ void f4add(float4& a, const float4& b) {
    a.x += b.x; a.y += b.y; a.z += b.z; a.w += b.w;
}

// packed-half2 dot product with f32 accumulate
static __device__ __forceinline__ float dot2(unsigned a, unsigned b, float c) {
#if __has_builtin(__builtin_amdgcn_fdot2)
    using h2v = __attribute__((ext_vector_type(2))) _Float16;
    return __builtin_amdgcn_fdot2(__builtin_bit_cast(h2v, a), __builtin_bit_cast(h2v, b), c, false);
#else
    __half2 ha = *(__half2*)&a, hb = *(__half2*)&b;
    float2 fa = __half22float2(ha), fb = __half22float2(hb);
    return fmaf(fa.x, fb.x, fmaf(fa.y, fb.y, c));
#endif
}

// ---------------- graph-structure kernels (run once per call) ----------------

// batch is sorted: per-graph counts via binary search, zero atomics.
__global__ __launch_bounds__(256) void k_gcnt(const int* __restrict__ batch, int* __restrict__ gcnt) {
    __shared__ int start[N_GRAPHS + 1];
    int g = threadIdx.x;
    int lo = 0, hi = N_NODES;
    while (lo < hi) { int mid = (lo + hi) >> 1; if (batch[mid] < g) lo = mid + 1; else hi = mid; }
    start[g] = lo;
    if (g == 0) start[N_GRAPHS] = N_NODES;
    __syncthreads();
    gcnt[g] = start[g + 1] - start[g];
}

// Pass 1: bin edges by dst octant (width 12800). Dense int2 appends.
__global__ __launch_bounds__(256) void k_bin(const int* __restrict__ src, const int* __restrict__ dst,
                                             int* __restrict__ gcur, int2* __restrict__ bins) {
    __shared__ int lcnt[NOCT];
    __shared__ int lbase[NOCT];
    const int t = threadIdx.x;
    const int NC = N_EDGES / 4 / 256;              // 3125 chunks of 1024 edges
    for (int chunk = blockIdx.x; chunk < NC; chunk += gridDim.x) {
        if (t < NOCT) lcnt[t] = 0;
        __syncthreads();
        int i4 = chunk * 256 + t;
        int4 d = ((const int4*)dst)[i4];
        int4 s = ((const int4*)src)[i4];
        int o0 = d.x / OCT_W, o1 = d.y / OCT_W, o2 = d.z / OCT_W, o3 = d.w / OCT_W;
        int r0 = atomicAdd(&lcnt[o0], 1);
        int r1 = atomicAdd(&lcnt[o1], 1);
        int r2 = atomicAdd(&lcnt[o2], 1);
        int r3 = atomicAdd(&lcnt[o3], 1);
        __syncthreads();
        if (t < NOCT) lbase[t] = lcnt[t] ? atomicAdd(&gcur[t], lcnt[t]) : 0;
        __syncthreads();
        bins[(size_t)o0 * BIN_CAP + lbase[o0] + r0] = make_int2(d.x, s.x);
        bins[(size_t)o1 * BIN_CAP + lbase[o1] + r1] = make_int2(d.y, s.y);
        bins[(size_t)o2 * BIN_CAP + lbase[o2] + r2] = make_int2(d.z, s.z);
        bins[(size_t)o3 * BIN_CAP + lbase[o3] + r3] = make_int2(d.w, s.w);
        __syncthreads();
    }
}

// Pass 2a: octant bins -> per-sub-bin packed lists (src | dst_local<<17).
__global__ __launch_bounds__(256) void k_bin2a(const int2* __restrict__ bins1, const int* __restrict__ gcur,
                                               int* __restrict__ gcur2, unsigned* __restrict__ bins2) {
    __shared__ int lcnt[SB_PER_OCT];
    __shared__ int lbase[SB_PER_OCT];
    const int o = blockIdx.x & 7;
    const int slice = blockIdx.x >> 3;             // 0..31
    const int t = threadIdx.x;
    const int n = gcur[o];
    const int2* bp = bins1 + (size_t)o * BIN_CAP;
    const int sbBase = o * SB_PER_OCT;
    for (int start = slice * 2048; start < n; start += 32 * 2048) {
        if (t < SB_PER_OCT) lcnt[t] = 0;
        __syncthreads();
        int r[8]; int sbl[8]; unsigned pk[8];
#pragma unroll
        for (int j = 0; j < 8; j++) {
            int idx = start + j * 256 + t;
            if (idx < n) {
                int2 e = bp[idx];
                sbl[j] = (e.x - o * OCT_W) >> 7;
                pk[j] = (unsigned)e.y | ((unsigned)(e.x & (SBW - 1)) << 17);
                r[j] = atomicAdd(&lcnt[sbl[j]], 1);
            } else sbl[j] = -1;
        }
        __syncthreads();
        if (t < SB_PER_OCT) lbase[t] = lcnt[t] ? atomicAdd(&gcur2[sbBase + t], lcnt[t]) : 0;
        __syncthreads();
#pragma unroll
        for (int j = 0; j < 8; j++)
            if (sbl[j] >= 0)
                bins2[(size_t)(sbBase + sbl[j]) * CAP2 + lbase[sbl[j]] + r[j]] = pk[j];
        __syncthreads();
    }
}

// Pass 2b: per sub-bin LDS counting sort by (dst_local, src_quartile).
// CSR for free + quartile-ordered edge segments.
__global__ __launch_bounds__(256) void k_bin2s(unsigned* __restrict__ bins2, const int* __restrict__ gcur2,
                                               int* __restrict__ degE, float* __restrict__ dinv,
                                               int* __restrict__ rowptr2) {
    __shared__ unsigned raw[CAP2];
    __shared__ unsigned srt[CAP2];
    __shared__ int cnt[NKEY];
    __shared__ int cur[NKEY];
    const int sb = blockIdx.x;
    const int t = threadIdx.x;
    const int base = sb * SBW;
    int n = gcur2[sb]; if (n > CAP2) n = CAP2;
    unsigned* seg = bins2 + (size_t)sb * CAP2;
    for (int i = t; i < n; i += 256) raw[i] = seg[i];
    for (int i = t; i < NKEY; i += 256) cnt[i] = 0;
    __syncthreads();
    for (int i = t; i < n; i += 256) {
        unsigned p = raw[i];
        int key = (int)(p >> 17) * 4 + (int)((p & 0x1FFFFu) / QDIV);
        atomicAdd(&cnt[key], 1);
    }
    __syncthreads();
    if (t == 0) {
        int run = 0;
        for (int i = 0; i < NKEY; i++) { cur[i] = run; run += cnt[i]; }
    }
    __syncthreads();
    if (t < SBW && base + t < N_NODES) {
        int deg = cnt[t * 4] + cnt[t * 4 + 1] + cnt[t * 4 + 2] + cnt[t * 4 + 3];
        degE[base + t]    = deg;
        dinv[base + t]    = rsqrtf((float)(deg + 1));       // +1 self-loop
        rowptr2[base + t] = sb * CAP2 + cur[t * 4];
    }
    __syncthreads();
    for (int i = t; i < n; i += 256) {
        unsigned p = raw[i];
        int key = (int)(p >> 17) * 4 + (int)((p & 0x1FFFFu) / QDIV);
        srt[atomicAdd(&cur[key], 1)] = p;
    }
    __syncthreads();
    for (int i = t; i < n; i += 256) seg[i] = srt[i];
}

// ---------------- per-layer kernels ----------------

// h0 = x @ Win + bin
__global__ __launch_bounds__(256) void k_h0(const float* __restrict__ x, const float* __restrict__ Win,
                                            const float* __restrict__ b, float* __restrict__ h) {
    int i = blockIdx.x * 256 + threadIdx.x;
    if (i >= N_NODES * HID) return;
    int v = i >> 6, j = i & 63;
    float acc = b[j];
#pragma unroll
    for (int k = 0; k < NODE_DIM; k++) acc += x[v * NODE_DIM + k] * Win[k * HID + j];
    h[i] = acc;
}

// y = fp16( (h @ W) * dinv[:,None] ) ; 64 nodes per block.
// h staged as packed half2 (8KB LDS), W staged fp32 (16KB LDS).
// Each lane hoists its W column as 32 packed-half2 REGISTERS (conflict-free
// ds_read_b32 + cvt_pkrtz, once per block). Per node: 8 broadcast ds_read_b128
// + 32 v_dot2_f32_f16 -> ~4x less per-node LDS+VALU than the fp32 version.
__global__ __launch_bounds__(256) void k_xw(const float* __restrict__ h, const float* __restrict__ W,
                                            const float* __restrict__ dinv, __half* __restrict__ y) {
    __shared__ unsigned Hs2[64][32];    // half2 pairs along k, 8KB
    __shared__ float Ws[HID][HID];      // 16KB
    __shared__ float sdv[64];
    const int t = threadIdx.x;
    const int nb = blockIdx.x * 64;
#pragma unroll
    for (int it = 0; it < 4; it++) {
        int i = t + it * 256;                       // float4 index
        ((float4*)Ws)[i] = ((const float4*)W)[i];
        int r = i >> 4, c4 = i & 15;
        int node = nb + r;
        float4 hv = make_float4(0.f, 0.f, 0.f, 0.f);
        if (node < N_NODES) hv = ((const float4*)h)[(size_t)node * 16 + c4];
        __half2 p0 = __floats2half2_rn(hv.x, hv.y);
        __half2 p1 = __floats2half2_rn(hv.z, hv.w);
        Hs2[r][c4 * 2 + 0] = *(unsigned*)&p0;
        Hs2[r][c4 * 2 + 1] = *(unsigned*)&p1;
    }
    if (t < 64) {
        int node = nb + t;
        sdv[t] = (node < N_NODES) ? dinv[node] : 0.f;
    }
    __syncthreads();
    const int j = t & 63;
    const int w = t >> 6;                           // wave 0..3
    unsigned wreg[32];                              // W column j, packed half2
#pragma unroll
    for (int kp = 0; kp < 32; kp++) {
        __half2 p = __floats2half2_rn(Ws[kp * 2 + 0][j], Ws[kp * 2 + 1][j]);
        wreg[kp] = *(unsigned*)&p;
    }
    for (int nn = 0; nn < 16; nn++) {
        int r = w * 16 + nn;
        int node = nb + r;
        if (node >= N_NODES) break;
        float acc = 0.f;
#pragma unroll
        for (int q = 0; q < 8; q++) {
            uint4 hp = ((const uint4*)&Hs2[r][0])[q];   // broadcast (uniform addr)
            acc = dot2(hp.x, wreg[q * 4 + 0], acc);
            acc = dot2(hp.y, wreg[q * 4 + 1], acc);
            acc = dot2(hp.z, wreg[q * 4 + 2], acc);
            acc = dot2(hp.w, wreg[q * 4 + 3], acc);
        }
        y[(size_t)node * HID + j] = __float2half(acc * sdv[r]);
    }
}

// c[v] = dinv[v]*(y[v] + sum_{in-edges} y[s]) + bias ; fused per-graph S1/S2 stats.
// One wave per node. fp16 rows = 128B = 8 lanes x uint4; lane-group q (8 lanes)
// gathers edge e+q from the sorted packed segment (src = p & 0x1FFFF).
// 32-edge unroll: 4 independent 1KB gathers in flight. f32 accumulate.
__global__ __launch_bounds__(256) void k_agg(const __half* __restrict__ y, const int* __restrict__ rowptr2,
                                             const int* __restrict__ degE, const unsigned* __restrict__ cols,
                                             const float* __restrict__ dinv, const float* __restrict__ bias,
                                             const int* __restrict__ batch, float* __restrict__ c,
                                             float* __restrict__ gS1, float* __restrict__ gS2) {
    __shared__ float sh1[4][HID];
    __shared__ float sh2[4][HID];
    __shared__ int shg[4];
    const int t = threadIdx.x;
    const int w = t >> 6;          // wave in block
    const int lane = t & 63;
    const int v = blockIdx.x * 4 + w;    // grid covers N_NODES exactly
    const int q = lane >> 3;       // edge group 0..7
    const int f8 = lane & 7;       // uint4 slot within 128B row
    const uint4* __restrict__ y16 = (const uint4*)y;

    float a[8] = {0.f,0.f,0.f,0.f,0.f,0.f,0.f,0.f};
    float b[8] = {0.f,0.f,0.f,0.f,0.f,0.f,0.f,0.f};

    auto unpack_add = [&](float* acc, uint4 u) {
        float2 f0 = __half22float2(*(const __half2*)&u.x);
        float2 f1 = __half22float2(*(const __half2*)&u.y);
        float2 f2 = __half22float2(*(const __half2*)&u.z);
        float2 f3 = __half22float2(*(const __half2*)&u.w);
        acc[0] += f0.x; acc[1] += f0.y;
        acc[2] += f1.x; acc[3] += f1.y;
        acc[4] += f2.x; acc[5] += f2.y;
        acc[6] += f3.x; acc[7] += f3.y;
    };

    if (q == 0) unpack_add(a, y16[(size_t)v * 8 + f8]);     // self-loop
    int e0 = rowptr2[v], e1 = e0 + degE[v];
    int e = e0;
    if (e + 31 < e1) {
        int s0 = cols[e + q] & 0x1FFFF, s1 = cols[e + 8 + q] & 0x1FFFF;
        int s2 = cols[e + 16 + q] & 0x1FFFF, s3 = cols[e + 24 + q] & 0x1FFFF;
        for (;;) {
            uint4 u0 = y16[(size_t)s0 * 8 + f8];
            uint4 u1 = y16[(size_t)s1 * 8 + f8];
            uint4 u2 = y16[(size_t)s2 * 8 + f8];
            uint4 u3 = y16[(size_t)s3 * 8 + f8];
            e += 32;
            bool more = (e + 31 < e1);
            if (more) {
                s0 = cols[e + q] & 0x1FFFF; s1 = cols[e + 8 + q] & 0x1FFFF;
                s2 = cols[e + 16 + q] & 0x1FFFF; s3 = cols[e + 24 + q] & 0x1FFFF;
            }
            unpack_add(a, u0);
            unpack_add(b, u1);
            unpack_add(a, u2);
            unpack_add(b, u3);
            if (!more) break;
        }
    }
    if (e + 15 < e1) {
        int s0 = cols[e + q] & 0x1FFFF, s1 = cols[e + 8 + q] & 0x1FFFF;
        uint4 u0 = y16[(size_t)s0 * 8 + f8];
        uint4 u1 = y16[(size_t)s1 * 8 + f8];
        unpack_add(a, u0);
        unpack_add(b, u1);
        e += 16;
    }
    if (e + 7 < e1) {
        unpack_add(a, y16[(size_t)(cols[e + q] & 0x1FFFF) * 8 + f8]);
        e += 8;
    }
    if (e + q < e1) {
        unpack_add(b, y16[(size_t)(cols[e + q] & 0x1FFFF) * 8 + f8]);
    }
#pragma unroll
    for (int k = 0; k < 8; k++) a[k] += b[k];
    // reduce across the 8 lane-groups (masks 8, 16, 32)
#pragma unroll
    for (int k = 0; k < 8; k++) {
        a[k] += __shfl_xor(a[k], 8);
        a[k] += __shfl_xor(a[k], 16);
        a[k] += __shfl_xor(a[k], 32);
    }

    if (q == 0) {   // lanes 0..7 hold features [f8*8 .. f8*8+7]
        float dv = dinv[v];
        float4 bb0 = ((const float4*)bias)[f8 * 2 + 0];
        float4 bb1 = ((const float4*)bias)[f8 * 2 + 1];
        float cv[8];
        cv[0] = dv * a[0] + bb0.x; cv[1] = dv * a[1] + bb0.y;
        cv[2] = dv * a[2] + bb0.z; cv[3] = dv * a[3] + bb0.w;
        cv[4] = dv * a[4] + bb1.x; cv[5] = dv * a[5] + bb1.y;
        cv[6] = dv * a[6] + bb1.z; cv[7] = dv * a[7] + bb1.w;
        float4* c4 = (float4*)c;
        c4[(size_t)v * 16 + f8 * 2 + 0] = make_float4(cv[0], cv[1], cv[2], cv[3]);
        c4[(size_t)v * 16 + f8 * 2 + 1] = make_float4(cv[4], cv[5], cv[6], cv[7]);
#pragma unroll
        for (int k = 0; k < 8; k++) {
            sh1[w][f8 * 8 + k] = cv[k];
            sh2[w][f8 * 8 + k] = cv[k] * cv[k];
        }
        if (f8 == 0) shg[w] = batch[v];
    }
    __syncthreads();
    if (w == 0) {   // one wave reduces block stats
        int g0 = shg[0];
        bool uni = (shg[1] == g0) && (shg[2] == g0) && (shg[3] == g0);
        if (uni) {
            float s1 = sh1[0][lane] + sh1[1][lane] + sh1[2][lane] + sh1[3][lane];
            float s2 = sh2[0][lane] + sh2[1][lane] + sh2[2][lane] + sh2[3][lane];
            atomicAdd(&gS1[g0 * HID + lane], s1);
            atomicAdd(&gS2[g0 * HID + lane], s2);
        } else {
#pragma unroll
            for (int ww = 0; ww < 4; ww++) {
                atomicAdd(&gS1[shg[ww] * HID + lane], sh1[ww][lane]);
                atomicAdd(&gS2[shg[ww] * HID + lane], sh2[ww][lane]);
            }
        }
    }
}

// per-graph mean / inv-std.  var = S2/cnt - 2*s*m^2 + s^2*m^2
__global__ __launch_bounds__(256) void k_stats(const float* __restrict__ gS1, const float* __restrict__ gS2,
                                               const int* __restrict__ gcnt, const float* __restrict__ gnS_l,
                                               float* __restrict__ gmean, float* __restrict__ ginv) {
    int i = blockIdx.x * 256 + threadIdx.x;
    if (i >= N_GRAPHS * HID) return;
    int g = i >> 6, j = i & 63;
    float cnt = fmaxf((float)gcnt[g], 1.f);
    float m = gS1[i] / cnt;
    float s = gnS_l[j];
    float var = gS2[i] / cnt - 2.f * s * m * m + s * s * m * m;
    gmean[i] = m;
    ginv[i] = rsqrtf(var + EPSV);
}

// h += relu(gnW*(c - s*mean)*invstd + gnB), float4 lanes; 16 nodes/block;
// optional block-reduced graph-emb accumulation.
__global__ __launch_bounds__(256) void k_update(const float* __restrict__ c, const int* __restrict__ batch,
                                                const float* __restrict__ gmean, const float* __restrict__ ginv,
                                                const float* __restrict__ gnW_l, const float* __restrict__ gnB_l,
                                                const float* __restrict__ gnS_l, float* __restrict__ h,
                                                float* __restrict__ gemb, int accum_emb) {
    __shared__ float4 shh[16][16];
    __shared__ int shg[16];
    __shared__ int uniS;
    int t = threadIdx.x;
    int i = blockIdx.x * 256 + t;          // float4 index; grid covers N_NODES*16 exactly
    int v = i >> 4, f = i & 15, r = t >> 4;
    int g = batch[v];
    float4 c4 = ((const float4*)c)[i];
    float4 m4 = ((const float4*)gmean)[g * 16 + f];
    float4 i4 = ((const float4*)ginv)[g * 16 + f];
    float4 w4 = ((const float4*)gnW_l)[f];
    float4 b4 = ((const float4*)gnB_l)[f];
    float4 s4 = ((const float4*)gnS_l)[f];
    float4 h4 = ((const float4*)h)[i];
    float4 hn;
    hn.x = h4.x + fmaxf(w4.x * (c4.x - s4.x * m4.x) * i4.x + b4.x, 0.f);
    hn.y = h4.y + fmaxf(w4.y * (c4.y - s4.y * m4.y) * i4.y + b4.y, 0.f);
    hn.z = h4.z + fmaxf(w4.z * (c4.z - s4.z * m4.z) * i4.z + b4.z, 0.f);
    hn.w = h4.w + fmaxf(w4.w * (c4.w - s4.w * m4.w) * i4.w + b4.w, 0.f);
    ((float4*)h)[i] = hn;
    if (accum_emb) {
        shh[r][f] = hn;
        if (f == 0) shg[r] = g;
        if (t == 0) uniS = 1;
        __syncthreads();
        if (t < 15 && shg[t + 1] != shg[0]) uniS = 0;
        __syncthreads();
        if (uniS) {
            if (t < 128) f4add(shh[t >> 4][t & 15], shh[(t >> 4) + 8][t & 15]);
            __syncthreads();
            if (t < 64) f4add(shh[t >> 4][t & 15], shh[(t >> 4) + 4][t & 15]);
            __syncthreads();
            if (t < 32) f4add(shh[t >> 4][t & 15], shh[(t >> 4) + 2][t & 15]);
            __syncthreads();
            if (t < 16) {
                f4add(shh[0][t], shh[1][t]);
                float4 s = shh[0][t];
                int g0 = shg[0];
                atomicAdd(&gemb[g0 * HID + t * 4 + 0], s.x);
                atomicAdd(&gemb[g0 * HID + t * 4 + 1], s.y);
                atomicAdd(&gemb[g0 * HID + t * 4 + 2], s.z);
                atomicAdd(&gemb[g0 * HID + t * 4 + 3], s.w);
            }
        } else if (t < 16) {
#pragma unroll
            for (int rr = 0; rr < 16; rr++) {
                float4 s = shh[rr][t];
                int gg = shg[rr];
                atomicAdd(&gemb[gg * HID + t * 4 + 0], s.x);
                atomicAdd(&gemb[gg * HID + t * 4 + 1], s.y);
                atomicAdd(&gemb[gg * HID + t * 4 + 2], s.z);
                atomicAdd(&gemb[gg * HID + t * 4 + 3], s.w);
            }
        }
    }
}

// classifier head: emb = gemb/cnt ; z = relu(emb@W1+b1) ; out = z@W2+b2
__global__ __launch_bounds__(64) void k_cls(const float* __restrict__ gemb, const int* __restrict__ gcnt,
                                            const float* __restrict__ W1, const float* __restrict__ b1,
                                            const float* __restrict__ W2, const float* __restrict__ b2,
                                            float* __restrict__ out) {
    __shared__ float emb[HID];
    __shared__ float z[HID];
    int g = blockIdx.x, j = threadIdx.x;
    float cnt = fmaxf((float)gcnt[g], 1.f);
    emb[j] = gemb[g * HID + j] / cnt;
    __syncthreads();
    float acc = b1[j];
    for (int k = 0; k < HID; k++) acc += emb[k] * W1[k * HID + j];
    z[j] = fmaxf(acc, 0.f);
    __syncthreads();
    if (j < 2) {
        float o = b2[j];
        for (int k = 0; k < HID; k++) o += z[k] * W2[k * 2 + j];
        out[g * 2 + j] = o;
    }
}

extern "C" void kernel_launch(void* const* d_in, const int* in_sizes, int n_in,
                              void* d_out, int out_size, void* d_ws, size_t ws_size,
                              hipStream_t stream) {
    const float* x     = (const float*)d_in[0];
    const int*   ei    = (const int*)d_in[1];
    const int*   src   = ei;
    const int*   dst   = ei + N_EDGES;
    const int*   batch = (const int*)d_in[2];
    const float* Win   = (const float*)d_in[3];
    const float* bin_  = (const float*)d_in[4];
    const float* convW = (const float*)d_in[5];
    const float* convB = (const float*)d_in[6];
    const float* gnW   = (const float*)d_in[7];
    const float* gnB   = (const float*)d_in[8];
    const float* gnS   = (const float*)d_in[9];
    const float* W1    = (const float*)d_in[10];
    const float* b1    = (const float*)d_in[11];
    const float* W2    = (const float*)d_in[12];
    const float* b2    = (const float*)d_in[13];
    float* out = (float*)d_out;

    char* ws = (char*)d_ws;
    size_t off = 0;
    auto alloc = [&](size_t bytes) -> void* {
        void* p = ws + off;
        off = (off + bytes + 255) & ~(size_t)255;
        return p;
    };
    // ---- zeroed region (one memset) ----
    int*   gcur   = (int*)alloc(NOCT * 4);
    int*   gcur2  = (int*)alloc((size_t)NSB * 4);
    float* gS1    = (float*)alloc((size_t)NLAY * N_GRAPHS * HID * 4);
    float* gS2    = (float*)alloc((size_t)NLAY * N_GRAPHS * HID * 4);
    float* gemb   = (float*)alloc((size_t)N_GRAPHS * HID * 4);
    size_t zeroBytes = off;
    // ---- rest ----
    int*   gcnt   = (int*)alloc((size_t)N_GRAPHS * 4);
    int*   degE   = (int*)alloc((size_t)N_NODES * 4);
    float* dinv   = (float*)alloc((size_t)N_NODES * 4);
    int*   rowptr2= (int*)alloc((size_t)N_NODES * 4);
    float* h      = (float*)alloc((size_t)N_NODES * HID * 4);   // 25.6 MB
    __half* y     = (__half*)alloc((size_t)N_NODES * HID * 2);  // 12.8 MB
    float* c      = (float*)alloc((size_t)N_NODES * HID * 4);   // 25.6 MB
    unsigned* bins2 = (unsigned*)alloc((size_t)NSB * CAP2 * 4); // 14.4 MB (persists all layers)
    float* gmean  = (float*)alloc((size_t)N_GRAPHS * HID * 4);
    float* ginv   = (float*)alloc((size_t)N_GRAPHS * HID * 4);
    // bins1 (30.7 MB int2) aliases h+y (38.4 MB): dead before k_h0/k_xw write them.
    int2*  bins1  = (int2*)h;
    (void)ws_size; (void)in_sizes; (void)n_in; (void)out_size;

    hipMemsetAsync(d_ws, 0, zeroBytes, stream);

    const int NHB = (N_NODES * HID + 255) / 256;     // 25000

    k_gcnt<<<1, 256, 0, stream>>>(batch, gcnt);
    k_bin<<<800, 256, 0, stream>>>(src, dst, gcur, bins1);
    k_bin2a<<<256, 256, 0, stream>>>(bins1, gcur, gcur2, bins2);
    k_bin2s<<<NSB, 256, 0, stream>>>(bins2, gcur2, degE, dinv, rowptr2);

    k_h0<<<NHB, 256, 0, stream>>>(x, Win, bin_, h);

    const int XWB = (N_NODES + 63) / 64;             // 1563
    for (int l = 0; l < NLAY; l++) {
        const float* Wl   = convW + (size_t)l * HID * HID;
        const float* bl   = convB + (size_t)l * HID;
        const float* gnWl = gnW + (size_t)l * HID;
        const float* gnBl = gnB + (size_t)l * HID;
        const float* gnSl = gnS + (size_t)l * HID;
        float* S1l = gS1 + (size_t)l * N_GRAPHS * HID;
        float* S2l = gS2 + (size_t)l * N_GRAPHS * HID;

        k_xw<<<XWB, 256, 0, stream>>>(h, Wl, dinv, y);
        k_agg<<<N_NODES / 4, 256, 0, stream>>>(y, rowptr2, degE, bins2, dinv, bl, batch, c, S1l, S2l);
        k_stats<<<(N_GRAPHS * HID + 255) / 256, 256, 0, stream>>>(S1l, S2l, gcnt, gnSl, gmean, ginv);
        k_update<<<N_NODES * 16 / 256, 256, 0, stream>>>(c, batch, gmean, ginv, gnWl, gnBl, gnSl, h, gemb,
                                                         (l == NLAY - 1) ? 1 : 0);
    }

    k_cls<<<N_GRAPHS, 64, 0, stream>>>(gemb, gcnt, W1, b1, W2, b2, out);
}

// Round 11
// 498.635 us; speedup vs baseline: 3.4698x; 1.1065x over previous
//
#include <hip/hip_runtime.h>
#include <hip/hip_fp16.h>

#define N_NODES 100000
#define N_EDGES 3200000
#define N_GRAPHS 256
#define NODE_DIM 7
#define HID 64
#define NLAY 3
#define EPSV 1e-5f

#define NOCT 8
#define OCT_W 12800                  // 100 sub-bins of 128 nodes per octant
#define BIN_CAP 480000               // per-octant int2 capacity (mean ~409.6K)
#define SBW 128                      // sub-bin width (nodes)
#define NSB 782                      // ceil(100000/128)
#define SB_PER_OCT 100
#define CAP2 4608                    // per-sub-bin packed capacity (mean 4096, +8 sigma)
#define QDIV 25000                   // src quartile divisor
#define NKEY (SBW * 4)               // (dst_local, quartile) sort keys

static __device__ __forceinline__ void f4add(float4& a, const float4& b) {
    a.x += b.x; a.y += b.y; a.z += b.z; a.w += b.w;
}

// packed-half2 dot product with f32 accumulate
static __device__ __forceinline__ float dot2(unsigned a, unsigned b, float c) {
#if __has_builtin(__builtin_amdgcn_fdot2)
    using h2v = __attribute__((ext_vector_type(2))) _Float16;
    return __builtin_amdgcn_fdot2(__builtin_bit_cast(h2v, a), __builtin_bit_cast(h2v, b), c, false);
#else
    __half2 ha = *(__half2*)&a, hb = *(__half2*)&b;
    float2 fa = __half22float2(ha), fb = __half22float2(hb);
    return fmaf(fa.x, fb.x, fmaf(fa.y, fb.y, c));
#endif
}

// ---------------- graph-structure kernels (run once per call) ----------------

__global__ __launch_bounds__(256) void k_gcnt(const int* __restrict__ batch, int* __restrict__ gcnt) {
    __shared__ int start[N_GRAPHS + 1];
    int g = threadIdx.x;
    int lo = 0, hi = N_NODES;
    while (lo < hi) { int mid = (lo + hi) >> 1; if (batch[mid] < g) lo = mid + 1; else hi = mid; }
    start[g] = lo;
    if (g == 0) start[N_GRAPHS] = N_NODES;
    __syncthreads();
    gcnt[g] = start[g + 1] - start[g];
}

// Pass 1: bin edges by dst octant (width 12800). Dense int2 appends.
__global__ __launch_bounds__(256) void k_bin(const int* __restrict__ src, const int* __restrict__ dst,
                                             int* __restrict__ gcur, int2* __restrict__ bins) {
    __shared__ int lcnt[NOCT];
    __shared__ int lbase[NOCT];
    const int t = threadIdx.x;
    const int NC = N_EDGES / 4 / 256;              // 3125 chunks of 1024 edges
    for (int chunk = blockIdx.x; chunk < NC; chunk += gridDim.x) {
        if (t < NOCT) lcnt[t] = 0;
        __syncthreads();
        int i4 = chunk * 256 + t;
        int4 d = ((const int4*)dst)[i4];
        int4 s = ((const int4*)src)[i4];
        int o0 = d.x / OCT_W, o1 = d.y / OCT_W, o2 = d.z / OCT_W, o3 = d.w / OCT_W;
        int r0 = atomicAdd(&lcnt[o0], 1);
        int r1 = atomicAdd(&lcnt[o1], 1);
        int r2 = atomicAdd(&lcnt[o2], 1);
        int r3 = atomicAdd(&lcnt[o3], 1);
        __syncthreads();
        if (t < NOCT) lbase[t] = lcnt[t] ? atomicAdd(&gcur[t], lcnt[t]) : 0;
        __syncthreads();
        bins[(size_t)o0 * BIN_CAP + lbase[o0] + r0] = make_int2(d.x, s.x);
        bins[(size_t)o1 * BIN_CAP + lbase[o1] + r1] = make_int2(d.y, s.y);
        bins[(size_t)o2 * BIN_CAP + lbase[o2] + r2] = make_int2(d.z, s.z);
        bins[(size_t)o3 * BIN_CAP + lbase[o3] + r3] = make_int2(d.w, s.w);
        __syncthreads();
    }
}

// Pass 2a: octant bins -> per-sub-bin packed lists (src | dst_local<<17).
__global__ __launch_bounds__(256) void k_bin2a(const int2* __restrict__ bins1, const int* __restrict__ gcur,
                                               int* __restrict__ gcur2, unsigned* __restrict__ bins2) {
    __shared__ int lcnt[SB_PER_OCT];
    __shared__ int lbase[SB_PER_OCT];
    const int o = blockIdx.x & 7;
    const int slice = blockIdx.x >> 3;             // 0..31
    const int t = threadIdx.x;
    const int n = gcur[o];
    const int2* bp = bins1 + (size_t)o * BIN_CAP;
    const int sbBase = o * SB_PER_OCT;
    for (int start = slice * 2048; start < n; start += 32 * 2048) {
        if (t < SB_PER_OCT) lcnt[t] = 0;
        __syncthreads();
        int r[8]; int sbl[8]; unsigned pk[8];
#pragma unroll
        for (int j = 0; j < 8; j++) {
            int idx = start + j * 256 + t;
            if (idx < n) {
                int2 e = bp[idx];
                sbl[j] = (e.x - o * OCT_W) >> 7;
                pk[j] = (unsigned)e.y | ((unsigned)(e.x & (SBW - 1)) << 17);
                r[j] = atomicAdd(&lcnt[sbl[j]], 1);
            } else sbl[j] = -1;
        }
        __syncthreads();
        if (t < SB_PER_OCT) lbase[t] = lcnt[t] ? atomicAdd(&gcur2[sbBase + t], lcnt[t]) : 0;
        __syncthreads();
#pragma unroll
        for (int j = 0; j < 8; j++)
            if (sbl[j] >= 0)
                bins2[(size_t)(sbBase + sbl[j]) * CAP2 + lbase[sbl[j]] + r[j]] = pk[j];
        __syncthreads();
    }
}

// Pass 2b: per sub-bin LDS counting sort by (dst_local, src_quartile).
__global__ __launch_bounds__(256) void k_bin2s(unsigned* __restrict__ bins2, const int* __restrict__ gcur2,
                                               int* __restrict__ degE, float* __restrict__ dinv,
                                               int* __restrict__ rowptr2) {
    __shared__ unsigned raw[CAP2];
    __shared__ unsigned srt[CAP2];
    __shared__ int cnt[NKEY];
    __shared__ int cur[NKEY];
    const int sb = blockIdx.x;
    const int t = threadIdx.x;
    const int base = sb * SBW;
    int n = gcur2[sb]; if (n > CAP2) n = CAP2;
    unsigned* seg = bins2 + (size_t)sb * CAP2;
    for (int i = t; i < n; i += 256) raw[i] = seg[i];
    for (int i = t; i < NKEY; i += 256) cnt[i] = 0;
    __syncthreads();
    for (int i = t; i < n; i += 256) {
        unsigned p = raw[i];
        int key = (int)(p >> 17) * 4 + (int)((p & 0x1FFFFu) / QDIV);
        atomicAdd(&cnt[key], 1);
    }
    __syncthreads();
    if (t == 0) {
        int run = 0;
        for (int i = 0; i < NKEY; i++) { cur[i] = run; run += cnt[i]; }
    }
    __syncthreads();
    if (t < SBW && base + t < N_NODES) {
        int deg = cnt[t * 4] + cnt[t * 4 + 1] + cnt[t * 4 + 2] + cnt[t * 4 + 3];
        degE[base + t]    = deg;
        dinv[base + t]    = rsqrtf((float)(deg + 1));       // +1 self-loop
        rowptr2[base + t] = sb * CAP2 + cur[t * 4];
    }
    __syncthreads();
    for (int i = t; i < n; i += 256) {
        unsigned p = raw[i];
        int key = (int)(p >> 17) * 4 + (int)((p & 0x1FFFFu) / QDIV);
        srt[atomicAdd(&cur[key], 1)] = p;
    }
    __syncthreads();
    for (int i = t; i < n; i += 256) seg[i] = srt[i];
}

// ---------------- per-layer kernels ----------------

// h0 = x @ Win + bin
__global__ __launch_bounds__(256) void k_h0(const float* __restrict__ x, const float* __restrict__ Win,
                                            const float* __restrict__ b, float* __restrict__ h) {
    int i = blockIdx.x * 256 + threadIdx.x;
    if (i >= N_NODES * HID) return;
    int v = i >> 6, j = i & 63;
    float acc = b[j];
#pragma unroll
    for (int k = 0; k < NODE_DIM; k++) acc += x[v * NODE_DIM + k] * Win[k * HID + j];
    h[i] = acc;
}

// y = fp16( (h @ W) * dinv[:,None] ) ; 64 nodes per block (proven round-10 form).
__global__ __launch_bounds__(256) void k_xw(const float* __restrict__ h, const float* __restrict__ W,
                                            const float* __restrict__ dinv, __half* __restrict__ y) {
    __shared__ unsigned Hs2[64][32];    // half2 pairs along k, 8KB
    __shared__ float Ws[HID][HID];      // 16KB
    __shared__ float sdv[64];
    const int t = threadIdx.x;
    const int nb = blockIdx.x * 64;
#pragma unroll
    for (int it = 0; it < 4; it++) {
        int i = t + it * 256;                       // float4 index
        ((float4*)Ws)[i] = ((const float4*)W)[i];
        int r = i >> 4, c4 = i & 15;
        int node = nb + r;
        float4 hv = make_float4(0.f, 0.f, 0.f, 0.f);
        if (node < N_NODES) hv = ((const float4*)h)[(size_t)node * 16 + c4];
        __half2 p0 = __floats2half2_rn(hv.x, hv.y);
        __half2 p1 = __floats2half2_rn(hv.z, hv.w);
        Hs2[r][c4 * 2 + 0] = *(unsigned*)&p0;
        Hs2[r][c4 * 2 + 1] = *(unsigned*)&p1;
    }
    if (t < 64) {
        int node = nb + t;
        sdv[t] = (node < N_NODES) ? dinv[node] : 0.f;
    }
    __syncthreads();
    const int j = t & 63;
    const int w = t >> 6;
    unsigned wreg[32];
#pragma unroll
    for (int kp = 0; kp < 32; kp++) {
        __half2 p = __floats2half2_rn(Ws[kp * 2 + 0][j], Ws[kp * 2 + 1][j]);
        wreg[kp] = *(unsigned*)&p;
    }
    for (int nn = 0; nn < 16; nn++) {
        int r = w * 16 + nn;
        int node = nb + r;
        if (node >= N_NODES) break;
        float acc = 0.f;
#pragma unroll
        for (int q = 0; q < 8; q++) {
            uint4 hp = ((const uint4*)&Hs2[r][0])[q];
            acc = dot2(hp.x, wreg[q * 4 + 0], acc);
            acc = dot2(hp.y, wreg[q * 4 + 1], acc);
            acc = dot2(hp.z, wreg[q * 4 + 2], acc);
            acc = dot2(hp.w, wreg[q * 4 + 3], acc);
        }
        y[(size_t)node * HID + j] = __float2half(acc * sdv[r]);
    }
}

// Fused: h += relu(graphnorm(c)) THEN y = fp16((h@W)*dinv) for the next layer.
// Staging loop applies the update elementwise and packs hn into the LDS tile.
__global__ __launch_bounds__(256) void k_upxw(const float* __restrict__ c, const int* __restrict__ batch,
                                              const float* __restrict__ gmean, const float* __restrict__ ginv,
                                              const float* __restrict__ gnW_l, const float* __restrict__ gnB_l,
                                              const float* __restrict__ gnS_l, float* __restrict__ h,
                                              const float* __restrict__ W, const float* __restrict__ dinv,
                                              __half* __restrict__ y) {
    __shared__ unsigned Hs2[64][32];    // 8KB
    __shared__ float Ws[HID][HID];      // 16KB
    __shared__ float sdv[64];
    const int t = threadIdx.x;
    const int nb = blockIdx.x * 64;
#pragma unroll
    for (int it = 0; it < 4; it++) {
        int i = t + it * 256;                       // float4 index
        ((float4*)Ws)[i] = ((const float4*)W)[i];
        int r = i >> 4, f = i & 15;
        int node = nb + r;
        float4 hn = make_float4(0.f, 0.f, 0.f, 0.f);
        if (node < N_NODES) {
            int g = batch[node];
            float4 h4 = ((const float4*)h)[(size_t)node * 16 + f];
            float4 cv = ((const float4*)c)[(size_t)node * 16 + f];
            float4 m4 = ((const float4*)gmean)[g * 16 + f];
            float4 i4 = ((const float4*)ginv)[g * 16 + f];
            float4 w4 = ((const float4*)gnW_l)[f];
            float4 b4 = ((const float4*)gnB_l)[f];
            float4 s4 = ((const float4*)gnS_l)[f];
            hn.x = h4.x + fmaxf(w4.x * (cv.x - s4.x * m4.x) * i4.x + b4.x, 0.f);
            hn.y = h4.y + fmaxf(w4.y * (cv.y - s4.y * m4.y) * i4.y + b4.y, 0.f);
            hn.z = h4.z + fmaxf(w4.z * (cv.z - s4.z * m4.z) * i4.z + b4.z, 0.f);
            hn.w = h4.w + fmaxf(w4.w * (cv.w - s4.w * m4.w) * i4.w + b4.w, 0.f);
            ((float4*)h)[(size_t)node * 16 + f] = hn;
        }
        __half2 p0 = __floats2half2_rn(hn.x, hn.y);
        __half2 p1 = __floats2half2_rn(hn.z, hn.w);
        Hs2[r][f * 2 + 0] = *(unsigned*)&p0;
        Hs2[r][f * 2 + 1] = *(unsigned*)&p1;
    }
    if (t < 64) {
        int node = nb + t;
        sdv[t] = (node < N_NODES) ? dinv[node] : 0.f;
    }
    __syncthreads();
    const int j = t & 63;
    const int w = t >> 6;
    unsigned wreg[32];
#pragma unroll
    for (int kp = 0; kp < 32; kp++) {
        __half2 p = __floats2half2_rn(Ws[kp * 2 + 0][j], Ws[kp * 2 + 1][j]);
        wreg[kp] = *(unsigned*)&p;
    }
    for (int nn = 0; nn < 16; nn++) {
        int r = w * 16 + nn;
        int node = nb + r;
        if (node >= N_NODES) break;
        float acc = 0.f;
#pragma unroll
        for (int q = 0; q < 8; q++) {
            uint4 hp = ((const uint4*)&Hs2[r][0])[q];
            acc = dot2(hp.x, wreg[q * 4 + 0], acc);
            acc = dot2(hp.y, wreg[q * 4 + 1], acc);
            acc = dot2(hp.z, wreg[q * 4 + 2], acc);
            acc = dot2(hp.w, wreg[q * 4 + 3], acc);
        }
        y[(size_t)node * HID + j] = __float2half(acc * sdv[r]);
    }
}

// c[v] = dinv[v]*(y[v] + sum y[s]) + bias ; fused stats. TWO nodes per wave:
// lanes 0-31 node A, 32-63 node B; 4 groups x 8 lanes per half; 4-deep unroll
// -> 8 independent 512B gathers in flight per wave (2x the 1-node form).
// cols read nontemporal (stream; don't evict y from L2). f32 accumulate.
__global__ __launch_bounds__(256) void k_agg(const __half* __restrict__ y, const int* __restrict__ rowptr2,
                                             const int* __restrict__ degE, const unsigned* __restrict__ cols,
                                             const float* __restrict__ dinv, const float* __restrict__ bias,
                                             const int* __restrict__ batch, float* __restrict__ c,
                                             float* __restrict__ gS1, float* __restrict__ gS2) {
    __shared__ float sh1[8][HID];
    __shared__ float sh2[8][HID];
    __shared__ int shg[8];
    const int t = threadIdx.x;
    const int w = t >> 6;          // wave 0..3
    const int lane = t & 63;
    const int half = lane >> 5;    // 0 = node A, 1 = node B
    const int hl = lane & 31;
    const int v = blockIdx.x * 8 + w * 2 + half;   // grid covers N_NODES exactly
    const int g4 = hl >> 3;        // edge group 0..3 within half
    const int f8 = hl & 7;         // uint4 slot within 128B row
    const uint4* __restrict__ y16 = (const uint4*)y;

    float a[8] = {0.f,0.f,0.f,0.f,0.f,0.f,0.f,0.f};
    float b[8] = {0.f,0.f,0.f,0.f,0.f,0.f,0.f,0.f};

    auto unpack_add = [&](float* acc, uint4 u) {
        float2 f0 = __half22float2(*(const __half2*)&u.x);
        float2 f1 = __half22float2(*(const __half2*)&u.y);
        float2 f2 = __half22float2(*(const __half2*)&u.z);
        float2 f3 = __half22float2(*(const __half2*)&u.w);
        acc[0] += f0.x; acc[1] += f0.y;
        acc[2] += f1.x; acc[3] += f1.y;
        acc[4] += f2.x; acc[5] += f2.y;
        acc[6] += f3.x; acc[7] += f3.y;
    };

    if (g4 == 0) unpack_add(a, y16[(size_t)v * 8 + f8]);    // self-loop
    const int e0 = rowptr2[v], e1 = e0 + degE[v];
    int e = e0 + g4;
    while (e + 12 < e1) {          // 4-deep: 4 independent gathers per lane chain
        int s0 = (int)(__builtin_nontemporal_load(cols + e)      & 0x1FFFFu);
        int s1 = (int)(__builtin_nontemporal_load(cols + e + 4)  & 0x1FFFFu);
        int s2 = (int)(__builtin_nontemporal_load(cols + e + 8)  & 0x1FFFFu);
        int s3 = (int)(__builtin_nontemporal_load(cols + e + 12) & 0x1FFFFu);
        uint4 u0 = y16[(size_t)s0 * 8 + f8];
        uint4 u1 = y16[(size_t)s1 * 8 + f8];
        uint4 u2 = y16[(size_t)s2 * 8 + f8];
        uint4 u3 = y16[(size_t)s3 * 8 + f8];
        unpack_add(a, u0);
        unpack_add(b, u1);
        unpack_add(a, u2);
        unpack_add(b, u3);
        e += 16;
    }
    while (e + 4 < e1) {
        int s0 = (int)(__builtin_nontemporal_load(cols + e)     & 0x1FFFFu);
        int s1 = (int)(__builtin_nontemporal_load(cols + e + 4) & 0x1FFFFu);
        uint4 u0 = y16[(size_t)s0 * 8 + f8];
        uint4 u1 = y16[(size_t)s1 * 8 + f8];
        unpack_add(a, u0);
        unpack_add(b, u1);
        e += 8;
    }
    if (e < e1) {
        int s0 = (int)(__builtin_nontemporal_load(cols + e) & 0x1FFFFu);
        unpack_add(a, y16[(size_t)s0 * 8 + f8]);
    }
#pragma unroll
    for (int k = 0; k < 8; k++) a[k] += b[k];
    // reduce across the 4 groups of this half (masks 8, 16 stay within half)
#pragma unroll
    for (int k = 0; k < 8; k++) {
        a[k] += __shfl_xor(a[k], 8);
        a[k] += __shfl_xor(a[k], 16);
    }

    const int row = w * 2 + half;
    if (g4 == 0) {   // lanes hl 0..7 of each half hold feats [f8*8 .. f8*8+7]
        float dv = dinv[v];
        float4 bb0 = ((const float4*)bias)[f8 * 2 + 0];
        float4 bb1 = ((const float4*)bias)[f8 * 2 + 1];
        float cv[8];
        cv[0] = dv * a[0] + bb0.x; cv[1] = dv * a[1] + bb0.y;
        cv[2] = dv * a[2] + bb0.z; cv[3] = dv * a[3] + bb0.w;
        cv[4] = dv * a[4] + bb1.x; cv[5] = dv * a[5] + bb1.y;
        cv[6] = dv * a[6] + bb1.z; cv[7] = dv * a[7] + bb1.w;
        float4* c4 = (float4*)c;
        c4[(size_t)v * 16 + f8 * 2 + 0] = make_float4(cv[0], cv[1], cv[2], cv[3]);
        c4[(size_t)v * 16 + f8 * 2 + 1] = make_float4(cv[4], cv[5], cv[6], cv[7]);
#pragma unroll
        for (int k = 0; k < 8; k++) {
            sh1[row][f8 * 8 + k] = cv[k];
            sh2[row][f8 * 8 + k] = cv[k] * cv[k];
        }
        if (f8 == 0) shg[row] = batch[v];
    }
    __syncthreads();
    if (w == 0) {   // one wave reduces block stats (8 nodes)
        int g0 = shg[0];
        bool uni = true;
#pragma unroll
        for (int ww = 1; ww < 8; ww++) uni = uni && (shg[ww] == g0);
        if (uni) {
            float s1 = 0.f, s2 = 0.f;
#pragma unroll
            for (int ww = 0; ww < 8; ww++) { s1 += sh1[ww][lane]; s2 += sh2[ww][lane]; }
            atomicAdd(&gS1[g0 * HID + lane], s1);
            atomicAdd(&gS2[g0 * HID + lane], s2);
        } else {
#pragma unroll
            for (int ww = 0; ww < 8; ww++) {
                atomicAdd(&gS1[shg[ww] * HID + lane], sh1[ww][lane]);
                atomicAdd(&gS2[shg[ww] * HID + lane], sh2[ww][lane]);
            }
        }
    }
}

// per-graph mean / inv-std.  var = S2/cnt - 2*s*m^2 + s^2*m^2
__global__ __launch_bounds__(256) void k_stats(const float* __restrict__ gS1, const float* __restrict__ gS2,
                                               const int* __restrict__ gcnt, const float* __restrict__ gnS_l,
                                               float* __restrict__ gmean, float* __restrict__ ginv) {
    int i = blockIdx.x * 256 + threadIdx.x;
    if (i >= N_GRAPHS * HID) return;
    int g = i >> 6, j = i & 63;
    float cnt = fmaxf((float)gcnt[g], 1.f);
    float m = gS1[i] / cnt;
    float s = gnS_l[j];
    float var = gS2[i] / cnt - 2.f * s * m * m + s * s * m * m;
    gmean[i] = m;
    ginv[i] = rsqrtf(var + EPSV);
}

// Final-layer update: h += relu(graphnorm(c)) + block-reduced gemb accumulation.
__global__ __launch_bounds__(256) void k_update(const float* __restrict__ c, const int* __restrict__ batch,
                                                const float* __restrict__ gmean, const float* __restrict__ ginv,
                                                const float* __restrict__ gnW_l, const float* __restrict__ gnB_l,
                                                const float* __restrict__ gnS_l, float* __restrict__ h,
                                                float* __restrict__ gemb) {
    __shared__ float4 shh[16][16];
    __shared__ int shg[16];
    __shared__ int uniS;
    int t = threadIdx.x;
    int i = blockIdx.x * 256 + t;          // float4 index; grid covers N_NODES*16 exactly
    int v = i >> 4, f = i & 15, r = t >> 4;
    int g = batch[v];
    float4 c4 = ((const float4*)c)[i];
    float4 m4 = ((const float4*)gmean)[g * 16 + f];
    float4 i4 = ((const float4*)ginv)[g * 16 + f];
    float4 w4 = ((const float4*)gnW_l)[f];
    float4 b4 = ((const float4*)gnB_l)[f];
    float4 s4 = ((const float4*)gnS_l)[f];
    float4 h4 = ((const float4*)h)[i];
    float4 hn;
    hn.x = h4.x + fmaxf(w4.x * (c4.x - s4.x * m4.x) * i4.x + b4.x, 0.f);
    hn.y = h4.y + fmaxf(w4.y * (c4.y - s4.y * m4.y) * i4.y + b4.y, 0.f);
    hn.z = h4.z + fmaxf(w4.z * (c4.z - s4.z * m4.z) * i4.z + b4.z, 0.f);
    hn.w = h4.w + fmaxf(w4.w * (c4.w - s4.w * m4.w) * i4.w + b4.w, 0.f);
    ((float4*)h)[i] = hn;
    shh[r][f] = hn;
    if (f == 0) shg[r] = g;
    if (t == 0) uniS = 1;
    __syncthreads();
    if (t < 15 && shg[t + 1] != shg[0]) uniS = 0;
    __syncthreads();
    if (uniS) {
        if (t < 128) f4add(shh[t >> 4][t & 15], shh[(t >> 4) + 8][t & 15]);
        __syncthreads();
        if (t < 64) f4add(shh[t >> 4][t & 15], shh[(t >> 4) + 4][t & 15]);
        __syncthreads();
        if (t < 32) f4add(shh[t >> 4][t & 15], shh[(t >> 4) + 2][t & 15]);
        __syncthreads();
        if (t < 16) {
            f4add(shh[0][t], shh[1][t]);
            float4 s = shh[0][t];
            int g0 = shg[0];
            atomicAdd(&gemb[g0 * HID + t * 4 + 0], s.x);
            atomicAdd(&gemb[g0 * HID + t * 4 + 1], s.y);
            atomicAdd(&gemb[g0 * HID + t * 4 + 2], s.z);
            atomicAdd(&gemb[g0 * HID + t * 4 + 3], s.w);
        }
    } else if (t < 16) {
#pragma unroll
        for (int rr = 0; rr < 16; rr++) {
            float4 s = shh[rr][t];
            int gg = shg[rr];
            atomicAdd(&gemb[gg * HID + t * 4 + 0], s.x);
            atomicAdd(&gemb[gg * HID + t * 4 + 1], s.y);
            atomicAdd(&gemb[gg * HID + t * 4 + 2], s.z);
            atomicAdd(&gemb[gg * HID + t * 4 + 3], s.w);
        }
    }
}

// classifier head: emb = gemb/cnt ; z = relu(emb@W1+b1) ; out = z@W2+b2
__global__ __launch_bounds__(64) void k_cls(const float* __restrict__ gemb, const int* __restrict__ gcnt,
                                            const float* __restrict__ W1, const float* __restrict__ b1,
                                            const float* __restrict__ W2, const float* __restrict__ b2,
                                            float* __restrict__ out) {
    __shared__ float emb[HID];
    __shared__ float z[HID];
    int g = blockIdx.x, j = threadIdx.x;
    float cnt = fmaxf((float)gcnt[g], 1.f);
    emb[j] = gemb[g * HID + j] / cnt;
    __syncthreads();
    float acc = b1[j];
    for (int k = 0; k < HID; k++) acc += emb[k] * W1[k * HID + j];
    z[j] = fmaxf(acc, 0.f);
    __syncthreads();
    if (j < 2) {
        float o = b2[j];
        for (int k = 0; k < HID; k++) o += z[k] * W2[k * 2 + j];
        out[g * 2 + j] = o;
    }
}

extern "C" void kernel_launch(void* const* d_in, const int* in_sizes, int n_in,
                              void* d_out, int out_size, void* d_ws, size_t ws_size,
                              hipStream_t stream) {
    const float* x     = (const float*)d_in[0];
    const int*   ei    = (const int*)d_in[1];
    const int*   src   = ei;
    const int*   dst   = ei + N_EDGES;
    const int*   batch = (const int*)d_in[2];
    const float* Win   = (const float*)d_in[3];
    const float* bin_  = (const float*)d_in[4];
    const float* convW = (const float*)d_in[5];
    const float* convB = (const float*)d_in[6];
    const float* gnW   = (const float*)d_in[7];
    const float* gnB   = (const float*)d_in[8];
    const float* gnS   = (const float*)d_in[9];
    const float* W1    = (const float*)d_in[10];
    const float* b1    = (const float*)d_in[11];
    const float* W2    = (const float*)d_in[12];
    const float* b2    = (const float*)d_in[13];
    float* out = (float*)d_out;

    char* ws = (char*)d_ws;
    size_t off = 0;
    auto alloc = [&](size_t bytes) -> void* {
        void* p = ws + off;
        off = (off + bytes + 255) & ~(size_t)255;
        return p;
    };
    // ---- zeroed region (one memset) ----
    int*   gcur   = (int*)alloc(NOCT * 4);
    int*   gcur2  = (int*)alloc((size_t)NSB * 4);
    float* gS1    = (float*)alloc((size_t)NLAY * N_GRAPHS * HID * 4);
    float* gS2    = (float*)alloc((size_t)NLAY * N_GRAPHS * HID * 4);
    float* gemb   = (float*)alloc((size_t)N_GRAPHS * HID * 4);
    size_t zeroBytes = off;
    // ---- rest ----
    int*   gcnt   = (int*)alloc((size_t)N_GRAPHS * 4);
    int*   degE   = (int*)alloc((size_t)N_NODES * 4);
    float* dinv   = (float*)alloc((size_t)N_NODES * 4);
    int*   rowptr2= (int*)alloc((size_t)N_NODES * 4);
    float* h      = (float*)alloc((size_t)N_NODES * HID * 4);   // 25.6 MB
    __half* y     = (__half*)alloc((size_t)N_NODES * HID * 2);  // 12.8 MB
    float* c      = (float*)alloc((size_t)N_NODES * HID * 4);   // 25.6 MB
    unsigned* bins2 = (unsigned*)alloc((size_t)NSB * CAP2 * 4); // 14.4 MB (persists all layers)
    float* gmean  = (float*)alloc((size_t)N_GRAPHS * HID * 4);
    float* ginv   = (float*)alloc((size_t)N_GRAPHS * HID * 4);
    // bins1 (30.7 MB int2) aliases h+y (38.4 MB): dead before k_h0/k_xw write them.
    int2*  bins1  = (int2*)h;
    (void)ws_size; (void)in_sizes; (void)n_in; (void)out_size;

    hipMemsetAsync(d_ws, 0, zeroBytes, stream);

    const int NHB = (N_NODES * HID + 255) / 256;     // 25000

    k_gcnt<<<1, 256, 0, stream>>>(batch, gcnt);
    k_bin<<<800, 256, 0, stream>>>(src, dst, gcur, bins1);
    k_bin2a<<<256, 256, 0, stream>>>(bins1, gcur, gcur2, bins2);
    k_bin2s<<<NSB, 256, 0, stream>>>(bins2, gcur2, degE, dinv, rowptr2);

    k_h0<<<NHB, 256, 0, stream>>>(x, Win, bin_, h);

    const int XWB = (N_NODES + 63) / 64;             // 1563
    k_xw<<<XWB, 256, 0, stream>>>(h, convW, dinv, y);   // layer 0 projection
    for (int l = 0; l < NLAY; l++) {
        const float* bl   = convB + (size_t)l * HID;
        const float* gnWl = gnW + (size_t)l * HID;
        const float* gnBl = gnB + (size_t)l * HID;
        const float* gnSl = gnS + (size_t)l * HID;
        float* S1l = gS1 + (size_t)l * N_GRAPHS * HID;
        float* S2l = gS2 + (size_t)l * N_GRAPHS * HID;

        k_agg<<<N_NODES / 8, 256, 0, stream>>>(y, rowptr2, degE, bins2, dinv, bl, batch, c, S1l, S2l);
        k_stats<<<(N_GRAPHS * HID + 255) / 256, 256, 0, stream>>>(S1l, S2l, gcnt, gnSl, gmean, ginv);
        if (l < NLAY - 1) {
            const float* Wn = convW + (size_t)(l + 1) * HID * HID;
            k_upxw<<<XWB, 256, 0, stream>>>(c, batch, gmean, ginv, gnWl, gnBl, gnSl, h, Wn, dinv, y);
        } else {
            k_update<<<N_NODES * 16 / 256, 256, 0, stream>>>(c, batch, gmean, ginv, gnWl, gnBl, gnSl,
                                                             h, gemb);
        }
    }

    k_cls<<<N_GRAPHS, 64, 0, stream>>>(gemb, gcnt, W1, b1, W2, b2, out);
}